// Round 5
// baseline (651.285 us; speedup 1.0000x reference)
//
#include <hip/hip_runtime.h>

// ---------------------------------------------------------------------------
// 2-layer GCN on MI355X.
// CSR via bucket-chunked reorder; edges within each node's list placed in
// src-chunk order (13 x 8192-node chunks) so concurrent waves sweep a narrow
// src band -> better L2 hit rate on the random G-row gathers.
// EBLK=65536 (49 blocks) to kill global-atomic contention on bucket counters.
// Aggregation: wave-per-node, quad-per-edge float4 gather, butterfly merge.
//   out[i] = relu(dinv[i]*(G[i] + sum_{s in in(i)} G[s]) + b), G = rowscale(X@W,dinv)
// Final linear head fused into layer-2 aggregation.
// ---------------------------------------------------------------------------

#define EBLK 65536   // edges per bucketing block (few blocks -> low atomic contention)
#define SEGCAP 6144  // LDS staging capacity for one bucket's edge segment

__global__ __launch_bounds__(256) void bcount_k(const int* __restrict__ dst,
                                                int* __restrict__ bcnt, int E, int NB) {
    __shared__ int h[1024];
    int t = threadIdx.x;
#pragma unroll
    for (int j = 0; j < 4; j++) h[t + 256 * j] = 0;
    __syncthreads();
    long base = (long)blockIdx.x * EBLK;
#pragma unroll 4
    for (int r = 0; r < EBLK / 256; r++) {
        long i = base + r * 256 + t;
        if (i < E) atomicAdd(&h[((unsigned)dst[i]) >> 7], 1);
    }
    __syncthreads();
    for (int j = t; j < NB; j += 256)
        if (h[j]) atomicAdd(&bcnt[j], h[j]);
}

__global__ __launch_bounds__(1024) void bscan_k(const int* __restrict__ bcnt,
                                                int* __restrict__ boff,
                                                int* __restrict__ bcur, int NB) {
    __shared__ int s[1024];
    int t = threadIdx.x;
    int v = (t < NB) ? bcnt[t] : 0;
    s[t] = v;
    __syncthreads();
    for (int d = 1; d < 1024; d <<= 1) {
        int x = (t >= d) ? s[t - d] : 0;
        __syncthreads();
        s[t] += x;
        __syncthreads();
    }
    if (t < NB) {
        boff[t + 1] = s[t];
        if (t == 0) boff[0] = 0;
        bcur[t] = s[t] - v;  // exclusive
    }
}

__global__ __launch_bounds__(256) void bfill_k(const int* __restrict__ src,
                                               const int* __restrict__ dst,
                                               int* __restrict__ bcur,
                                               int* __restrict__ ebuf, int E, int NB) {
    __shared__ int h[1024];
    __shared__ int bbase[1024];
    __shared__ int rank[1024];
    int t = threadIdx.x;
#pragma unroll
    for (int j = 0; j < 4; j++) { h[t + 256 * j] = 0; rank[t + 256 * j] = 0; }
    __syncthreads();
    long base = (long)blockIdx.x * EBLK;
#pragma unroll 4
    for (int r = 0; r < EBLK / 256; r++) {
        long i = base + r * 256 + t;
        if (i < E) atomicAdd(&h[((unsigned)dst[i]) >> 7], 1);
    }
    __syncthreads();
    for (int j = t; j < NB; j += 256)
        if (h[j]) bbase[j] = atomicAdd(&bcur[j], h[j]);
    __syncthreads();
#pragma unroll 4
    for (int r = 0; r < EBLK / 256; r++) {
        long i = base + r * 256 + t;
        if (i < E) {
            int d = dst[i];
            int b = ((unsigned)d) >> 7;
            int rk = atomicAdd(&rank[b], 1);
            ebuf[bbase[b] + rk] = src[i] | ((d & 127) << 20);
        }
    }
}

// One block per bucket: exact per-node CSR + offsets + dinv. The bucket's
// edge segment is staged in LDS; reorder runs in 13 src-chunk passes so each
// node's edge list ends up sorted by src chunk (band-sweep locality in agg).
__global__ __launch_bounds__(256) void csr_k(const int* __restrict__ ebuf,
                                             const int* __restrict__ boff,
                                             int* __restrict__ off,
                                             int* __restrict__ csr,
                                             float* __restrict__ dinv, int n, int E) {
    __shared__ int seg[SEGCAP];
    __shared__ int cnt[128];
    __shared__ int pre[128];
    __shared__ int cur[128];
    int t = threadIdx.x;
    if (t < 128) cnt[t] = 0;
    int b = blockIdx.x;
    int s0 = boff[b], s1 = boff[b + 1];
    int len = s1 - s0;
    bool inl = (len <= SEGCAP);
    if (inl)
        for (int i = t; i < len; i += 256) seg[i] = ebuf[s0 + i];
    const int* p = inl ? (const int*)seg : (ebuf + s0);
    __syncthreads();
    for (int i = t; i < len; i += 256)
        atomicAdd(&cnt[((unsigned)p[i]) >> 20], 1);
    __syncthreads();
    if (t < 128) pre[t] = cnt[t];
    __syncthreads();
    for (int d = 1; d < 128; d <<= 1) {
        int v = (t >= d && t < 128) ? pre[t - d] : 0;
        __syncthreads();
        if (t < 128) pre[t] += v;
        __syncthreads();
    }
    if (t < 128) {
        int excl = pre[t] - cnt[t];
        cur[t] = excl;
        int gn = (b << 7) + t;
        if (gn < n) {
            off[gn] = s0 + excl;
            dinv[gn] = rsqrtf((float)(cnt[t] + 1));
        }
    }
    if (t == 0 && b == gridDim.x - 1) off[n] = E;
    __syncthreads();
    int nchunk = (n + 8191) >> 13;
    for (int c = 0; c < nchunk; c++) {
        for (int i = t; i < len; i += 256) {
            int v = p[i];
            int s = v & 0xFFFFF;
            if ((s >> 13) == c) {
                int l = ((unsigned)v) >> 20;
                int rk = atomicAdd(&cur[l], 1);
                csr[s0 + rk] = s;
            }
        }
        __syncthreads();
    }
}

// G[r][:] = dinv[r] * (X[r][:] @ W).  Thread-per-row, W staged in LDS.
__global__ __launch_bounds__(256) void gemm64_scale_k(
    const float* __restrict__ X, const float* __restrict__ W,
    const float* __restrict__ dinv, float* __restrict__ G, int n) {
    __shared__ float wl[64 * 64];
    int t = threadIdx.x;
#pragma unroll
    for (int u = 0; u < 16; u++) wl[t + 256 * u] = W[t + 256 * u];
    __syncthreads();
    int r = blockIdx.x * 256 + t;
    if (r >= n) return;

    const float4* xp = (const float4*)(X + (size_t)r * 64);
    float4 acc[16];
#pragma unroll
    for (int j = 0; j < 16; j++) acc[j] = make_float4(0.f, 0.f, 0.f, 0.f);

    for (int i = 0; i < 16; i++) {
        float4 xv = xp[i];
#pragma unroll
        for (int c = 0; c < 4; c++) {
            float xk = (c == 0) ? xv.x : (c == 1) ? xv.y : (c == 2) ? xv.z : xv.w;
            const float4* wr = (const float4*)(wl + (i * 4 + c) * 64);
#pragma unroll
            for (int j = 0; j < 16; j++) {
                float4 wv = wr[j];
                acc[j].x = fmaf(xk, wv.x, acc[j].x);
                acc[j].y = fmaf(xk, wv.y, acc[j].y);
                acc[j].z = fmaf(xk, wv.z, acc[j].z);
                acc[j].w = fmaf(xk, wv.w, acc[j].w);
            }
        }
    }
    float sc = dinv[r];
    float4* gp = (float4*)(G + (size_t)r * 64);
#pragma unroll
    for (int j = 0; j < 16; j++) {
        float4 v = acc[j];
        v.x *= sc; v.y *= sc; v.z *= sc; v.w *= sc;
        gp[j] = v;
    }
}

__device__ inline float4 ld4(const float* p) { return *(const float4*)p; }
__device__ inline void add4(float4& a, float4 g) {
    a.x += g.x; a.y += g.y; a.z += g.z; a.w += g.w;
}
__device__ inline void bfly4(float4& a, int m) {
    a.x += __shfl_xor(a.x, m);
    a.y += __shfl_xor(a.y, m);
    a.z += __shfl_xor(a.z, m);
    a.w += __shfl_xor(a.w, m);
}

// Wave-per-node aggregation, quad-per-edge float4 gather.
// lane = 16*q + fcol; quad q handles edge u+q; 16 lanes x float4 = 256B row.
// FINAL=0: Out[node][:] = relu(dinv*acc + bias)
// FINAL=1: Out[node] = relu(...) . Wl + bl
template <int FINAL>
__global__ __launch_bounds__(256) void agg_k(
    const float* __restrict__ G, const int* __restrict__ csr,
    const int* __restrict__ off, const float* __restrict__ dinv,
    const float* __restrict__ bias, const float* __restrict__ Wl,
    const float* __restrict__ bl, float* __restrict__ Out, int n) {
    int lane = threadIdx.x & 63;
    int wid = threadIdx.x >> 6;
    int node = blockIdx.x * 4 + wid;
    if (node >= n) return;

    int q = lane >> 4;
    int fl = (lane & 15) << 2;  // feature base for this lane's float4

    float4 a = make_float4(0.f, 0.f, 0.f, 0.f);
    if (q == 0) a = ld4(G + (size_t)node * 64 + fl);  // self-loop term

    int s0 = off[node], s1 = off[node + 1];
    for (int base = s0; base < s1; base += 64) {
        int m = s1 - base;
        if (m > 64) m = 64;
        int e = (lane < m) ? csr[base + lane] : 0;
        int u = 0;
        for (; u + 16 <= m; u += 16) {
            int e0 = __shfl(e, u + q);
            int e1 = __shfl(e, u + 4 + q);
            int e2 = __shfl(e, u + 8 + q);
            int e3 = __shfl(e, u + 12 + q);
            float4 g0 = ld4(G + (size_t)e0 * 64 + fl);
            float4 g1 = ld4(G + (size_t)e1 * 64 + fl);
            float4 g2 = ld4(G + (size_t)e2 * 64 + fl);
            float4 g3 = ld4(G + (size_t)e3 * 64 + fl);
            add4(a, g0); add4(a, g1); add4(a, g2); add4(a, g3);
        }
        for (; u + 4 <= m; u += 4) {
            int e0 = __shfl(e, u + q);
            add4(a, ld4(G + (size_t)e0 * 64 + fl));
        }
        if (u < m) {  // tail of 1..3 edges (u, m wave-uniform)
            int e0 = __shfl(e, (u + q < m) ? (u + q) : 0);
            if (u + q < m) add4(a, ld4(G + (size_t)e0 * 64 + fl));
        }
    }
    // merge quads: butterfly across lane bits 4,5
    bfly4(a, 16);
    bfly4(a, 32);

    float di = dinv[node];
    float4 bv = ld4(bias + fl);
    float4 v;
    v.x = fmaxf(fmaf(di, a.x, bv.x), 0.f);
    v.y = fmaxf(fmaf(di, a.y, bv.y), 0.f);
    v.z = fmaxf(fmaf(di, a.z, bv.z), 0.f);
    v.w = fmaxf(fmaf(di, a.w, bv.w), 0.f);

    if (FINAL) {
        float4 wv = ld4(Wl + fl);
        float p = v.x * wv.x + v.y * wv.y + v.z * wv.z + v.w * wv.w;
#pragma unroll
        for (int d = 8; d > 0; d >>= 1) p += __shfl_xor(p, d);
        if (lane == 0) Out[node] = p + bl[0];
    } else {
        if (q == 0) *(float4*)(Out + (size_t)node * 64 + fl) = v;
    }
}

extern "C" void kernel_launch(void* const* d_in, const int* in_sizes, int n_in,
                              void* d_out, int out_size, void* d_ws, size_t ws_size,
                              hipStream_t stream) {
    const float* x  = (const float*)d_in[0];
    const int*   ei = (const int*)d_in[1];
    const float* W1 = (const float*)d_in[2];
    const float* b1 = (const float*)d_in[3];
    const float* W2 = (const float*)d_in[4];
    const float* b2 = (const float*)d_in[5];
    const float* Wl = (const float*)d_in[6];
    const float* bl = (const float*)d_in[7];

    const int N = in_sizes[0] / 64;
    const int E = in_sizes[1] / 2;
    const int* src = ei;
    const int* dst = ei + E;
    const int NB = (N + 127) >> 7;         // 782 buckets (<=1024 assumed)
    const int FB = (E + EBLK - 1) / EBLK;  // 49

    char* w = (char*)d_ws;
    size_t o = 0;
    auto take = [&](size_t bytes) {
        void* p = w + o;
        o = (o + bytes + 255) & ~(size_t)255;
        return p;
    };
    int*   bcnt = (int*)take((size_t)NB * 4);
    int*   bcur = (int*)take((size_t)NB * 4);
    int*   boff = (int*)take((size_t)(NB + 1) * 4);
    float* dinv = (float*)take((size_t)N * 4);
    int*   off  = (int*)take((size_t)(N + 1) * 4);
    int*   ebuf = (int*)take((size_t)E * 4);
    int*   csr  = (int*)take((size_t)E * 4);
    float* bufA = (float*)take((size_t)N * 64 * 4);
    float* bufB = (float*)take((size_t)N * 64 * 4);

    hipMemsetAsync(bcnt, 0, (size_t)NB * 4, stream);
    bcount_k<<<FB, 256, 0, stream>>>(dst, bcnt, E, NB);
    bscan_k<<<1, 1024, 0, stream>>>(bcnt, boff, bcur, NB);
    bfill_k<<<FB, 256, 0, stream>>>(src, dst, bcur, ebuf, E, NB);
    csr_k<<<NB, 256, 0, stream>>>(ebuf, boff, off, csr, dinv, N, E);

    // Layer 1
    gemm64_scale_k<<<(N + 255) / 256, 256, 0, stream>>>(x, W1, dinv, bufA, N);
    agg_k<0><<<(N + 3) / 4, 256, 0, stream>>>(bufA, csr, off, dinv, b1, nullptr,
                                              nullptr, bufB, N);
    // Layer 2 + fused linear head
    gemm64_scale_k<<<(N + 255) / 256, 256, 0, stream>>>(bufB, W2, dinv, bufA, N);
    agg_k<1><<<(N + 3) / 4, 256, 0, stream>>>(bufA, csr, off, dinv, b2, Wl, bl,
                                              (float*)d_out, N);
}

// Round 7
// 446.683 us; speedup vs baseline: 1.4580x; 1.4580x over previous
//
#include <hip/hip_runtime.h>

// ---------------------------------------------------------------------------
// 2-layer GCN on MI355X.
//   out[i] = relu(dinv[i]*(G[i] + sum_{s in in(i)} G[s]) + b), G = rowscale(X@W,dinv)
// Preprocessing (per launch):
//   bfill2_k: 391 blocks x 8192 edges; LDS histogram over 782 fixed-capacity
//             buckets (dst>>7, CAP=6144), one global atomic per (block,bucket)
//             chunk reserve, packed write  src | (dst&127)<<20.
//   csr_k:    block-per-bucket, LDS-staged segment, count+scan -> per-node
//             offS/offE/dinv; reorder in 13 src-chunks so each node's edge
//             list is src-banded (L2 band-sweep during aggregation).
// Aggregation: wave-per-node, quad-per-edge float4 gather, butterfly merge.
// Final linear head fused into layer-2 aggregation.
// ---------------------------------------------------------------------------

#define EBLK 8192  // edges per bucketing block
#define CAP 6144   // bucket capacity (mean 4092, +32 sigma)

__global__ __launch_bounds__(256) void bfill2_k(const int* __restrict__ src,
                                                const int* __restrict__ dst,
                                                int* __restrict__ bcur,
                                                int* __restrict__ ebuf, int E, int NB) {
    __shared__ int h[1024];
    __shared__ int bbase[1024];
    __shared__ int rank[1024];
    int t = threadIdx.x;
#pragma unroll
    for (int j = 0; j < 4; j++) { h[t + 256 * j] = 0; rank[t + 256 * j] = 0; }
    __syncthreads();
    int base = blockIdx.x * EBLK;
#pragma unroll 4
    for (int r = 0; r < EBLK / 256; r++) {
        int i = base + r * 256 + t;
        if (i < E) atomicAdd(&h[((unsigned)dst[i]) >> 7], 1);
    }
    __syncthreads();
    for (int j = t; j < NB; j += 256)
        if (h[j]) bbase[j] = atomicAdd(&bcur[j], h[j]);
    __syncthreads();
#pragma unroll 4
    for (int r = 0; r < EBLK / 256; r++) {
        int i = base + r * 256 + t;
        if (i < E) {
            int d = dst[i];
            int b = ((unsigned)d) >> 7;
            int rk = atomicAdd(&rank[b], 1);
            int pos = bbase[b] + rk;
            if (pos < CAP) ebuf[(size_t)b * CAP + pos] = src[i] | ((d & 127) << 20);
        }
    }
}

// Block-per-bucket: exact per-node CSR (within bucket's fixed window) +
// offS/offE + dinv. Segment staged in LDS; reorder in 13 src-chunk passes.
__global__ __launch_bounds__(256) void csr_k(const int* __restrict__ ebuf,
                                             const int* __restrict__ bcur,
                                             int* __restrict__ offS,
                                             int* __restrict__ offE,
                                             int* __restrict__ csr,
                                             float* __restrict__ dinv, int n) {
    __shared__ int seg[CAP];  // 24 KiB
    __shared__ int cnt[128];
    __shared__ int pre[128];
    __shared__ int cur[128];
    int t = threadIdx.x;
    if (t < 128) cnt[t] = 0;
    int b = blockIdx.x;
    int len = bcur[b];
    if (len > CAP) len = CAP;
    int s0 = b * CAP;
    for (int i = t; i < len; i += 256) seg[i] = ebuf[s0 + i];
    __syncthreads();
    for (int i = t; i < len; i += 256)
        atomicAdd(&cnt[((unsigned)seg[i]) >> 20], 1);
    __syncthreads();
    if (t < 128) pre[t] = cnt[t];
    __syncthreads();
    for (int d = 1; d < 128; d <<= 1) {
        int v = (t >= d && t < 128) ? pre[t - d] : 0;
        __syncthreads();
        if (t < 128) pre[t] += v;
        __syncthreads();
    }
    if (t < 128) {
        int excl = pre[t] - cnt[t];
        cur[t] = excl;
        int gn = (b << 7) + t;
        if (gn < n) {
            offS[gn] = s0 + excl;
            offE[gn] = s0 + excl + cnt[t];
            dinv[gn] = rsqrtf((float)(cnt[t] + 1));
        }
    }
    __syncthreads();
    int nchunk = (n + 8191) >> 13;  // 13 for n=100000
    for (int c = 0; c < nchunk; c++) {
        for (int i = t; i < len; i += 256) {
            int v = seg[i];
            int s = v & 0xFFFFF;
            if ((s >> 13) == c) {
                int l = ((unsigned)v) >> 20;
                int rk = atomicAdd(&cur[l], 1);
                csr[s0 + rk] = s;
            }
        }
        __syncthreads();
    }
}

// G[r][:] = dinv[r] * (X[r][:] @ W).  Thread-per-row, W staged in LDS.
__global__ __launch_bounds__(256) void gemm64_scale_k(
    const float* __restrict__ X, const float* __restrict__ W,
    const float* __restrict__ dinv, float* __restrict__ G, int n) {
    __shared__ float wl[64 * 64];
    int t = threadIdx.x;
#pragma unroll
    for (int u = 0; u < 16; u++) wl[t + 256 * u] = W[t + 256 * u];
    __syncthreads();
    int r = blockIdx.x * 256 + t;
    if (r >= n) return;

    const float4* xp = (const float4*)(X + (size_t)r * 64);
    float4 acc[16];
#pragma unroll
    for (int j = 0; j < 16; j++) acc[j] = make_float4(0.f, 0.f, 0.f, 0.f);

    for (int i = 0; i < 16; i++) {
        float4 xv = xp[i];
#pragma unroll
        for (int c = 0; c < 4; c++) {
            float xk = (c == 0) ? xv.x : (c == 1) ? xv.y : (c == 2) ? xv.z : xv.w;
            const float4* wr = (const float4*)(wl + (i * 4 + c) * 64);
#pragma unroll
            for (int j = 0; j < 16; j++) {
                float4 wv = wr[j];
                acc[j].x = fmaf(xk, wv.x, acc[j].x);
                acc[j].y = fmaf(xk, wv.y, acc[j].y);
                acc[j].z = fmaf(xk, wv.z, acc[j].z);
                acc[j].w = fmaf(xk, wv.w, acc[j].w);
            }
        }
    }
    float sc = dinv[r];
    float4* gp = (float4*)(G + (size_t)r * 64);
#pragma unroll
    for (int j = 0; j < 16; j++) {
        float4 v = acc[j];
        v.x *= sc; v.y *= sc; v.z *= sc; v.w *= sc;
        gp[j] = v;
    }
}

__device__ inline float4 ld4(const float* p) { return *(const float4*)p; }
__device__ inline void add4(float4& a, float4 g) {
    a.x += g.x; a.y += g.y; a.z += g.z; a.w += g.w;
}
__device__ inline void bfly4(float4& a, int m) {
    a.x += __shfl_xor(a.x, m);
    a.y += __shfl_xor(a.y, m);
    a.z += __shfl_xor(a.z, m);
    a.w += __shfl_xor(a.w, m);
}

// Wave-per-node aggregation, quad-per-edge float4 gather.
// lane = 16*q + fcol; quad q handles edge u+q; 16 lanes x float4 = 256B row.
// FINAL=0: Out[node][:] = relu(dinv*acc + bias)
// FINAL=1: Out[node] = relu(...) . Wl + bl
template <int FINAL>
__global__ __launch_bounds__(256) void agg_k(
    const float* __restrict__ G, const int* __restrict__ csr,
    const int* __restrict__ offS, const int* __restrict__ offE,
    const float* __restrict__ dinv, const float* __restrict__ bias,
    const float* __restrict__ Wl, const float* __restrict__ bl,
    float* __restrict__ Out, int n) {
    int lane = threadIdx.x & 63;
    int wid = threadIdx.x >> 6;
    int node = blockIdx.x * 4 + wid;
    if (node >= n) return;

    int q = lane >> 4;
    int fl = (lane & 15) << 2;  // feature base for this lane's float4

    float4 a = make_float4(0.f, 0.f, 0.f, 0.f);
    if (q == 0) a = ld4(G + (size_t)node * 64 + fl);  // self-loop term

    int s0 = offS[node], s1 = offE[node];
    for (int base = s0; base < s1; base += 64) {
        int m = s1 - base;
        if (m > 64) m = 64;
        int e = (lane < m) ? csr[base + lane] : 0;
        int u = 0;
        for (; u + 16 <= m; u += 16) {
            int e0 = __shfl(e, u + q);
            int e1 = __shfl(e, u + 4 + q);
            int e2 = __shfl(e, u + 8 + q);
            int e3 = __shfl(e, u + 12 + q);
            float4 g0 = ld4(G + (size_t)e0 * 64 + fl);
            float4 g1 = ld4(G + (size_t)e1 * 64 + fl);
            float4 g2 = ld4(G + (size_t)e2 * 64 + fl);
            float4 g3 = ld4(G + (size_t)e3 * 64 + fl);
            add4(a, g0); add4(a, g1); add4(a, g2); add4(a, g3);
        }
        for (; u + 4 <= m; u += 4) {
            int e0 = __shfl(e, u + q);
            add4(a, ld4(G + (size_t)e0 * 64 + fl));
        }
        if (u < m) {  // tail of 1..3 edges (u, m wave-uniform)
            int e0 = __shfl(e, (u + q < m) ? (u + q) : 0);
            if (u + q < m) add4(a, ld4(G + (size_t)e0 * 64 + fl));
        }
    }
    // merge quads: butterfly across lane bits 4,5
    bfly4(a, 16);
    bfly4(a, 32);

    float di = dinv[node];
    float4 bv = ld4(bias + fl);
    float4 v;
    v.x = fmaxf(fmaf(di, a.x, bv.x), 0.f);
    v.y = fmaxf(fmaf(di, a.y, bv.y), 0.f);
    v.z = fmaxf(fmaf(di, a.z, bv.z), 0.f);
    v.w = fmaxf(fmaf(di, a.w, bv.w), 0.f);

    if (FINAL) {
        float4 wv = ld4(Wl + fl);
        float p = v.x * wv.x + v.y * wv.y + v.z * wv.z + v.w * wv.w;
#pragma unroll
        for (int d = 8; d > 0; d >>= 1) p += __shfl_xor(p, d);
        if (lane == 0) Out[node] = p + bl[0];
    } else {
        if (q == 0) *(float4*)(Out + (size_t)node * 64 + fl) = v;
    }
}

extern "C" void kernel_launch(void* const* d_in, const int* in_sizes, int n_in,
                              void* d_out, int out_size, void* d_ws, size_t ws_size,
                              hipStream_t stream) {
    const float* x  = (const float*)d_in[0];
    const int*   ei = (const int*)d_in[1];
    const float* W1 = (const float*)d_in[2];
    const float* b1 = (const float*)d_in[3];
    const float* W2 = (const float*)d_in[4];
    const float* b2 = (const float*)d_in[5];
    const float* Wl = (const float*)d_in[6];
    const float* bl = (const float*)d_in[7];

    const int N = in_sizes[0] / 64;
    const int E = in_sizes[1] / 2;
    const int* src = ei;
    const int* dst = ei + E;
    const int NB = (N + 127) >> 7;         // 782 buckets (<=1024 assumed)
    const int FB = (E + EBLK - 1) / EBLK;  // 391

    char* w = (char*)d_ws;
    size_t o = 0;
    auto take = [&](size_t bytes) {
        void* p = w + o;
        o = (o + bytes + 255) & ~(size_t)255;
        return p;
    };
    int*   bcur = (int*)take((size_t)NB * 4);
    float* dinv = (float*)take((size_t)N * 4);
    int*   offS = (int*)take((size_t)N * 4);
    int*   offE = (int*)take((size_t)N * 4);
    int*   csr  = (int*)take((size_t)NB * CAP * 4);   // 19.2 MB (holey)
    float* bufB = (float*)take((size_t)N * 64 * 4);   // 25.6 MB
    // ebuf is dead after csr_k; alias it with bufA (gemm1 runs after csr_k).
    char*  ovl  = (char*)take((size_t)N * 64 * 4);    // 25.6 MB >= ebuf 19.2 MB
    int*   ebuf = (int*)ovl;
    float* bufA = (float*)ovl;

    hipMemsetAsync(bcur, 0, (size_t)NB * 4, stream);
    bfill2_k<<<FB, 256, 0, stream>>>(src, dst, bcur, ebuf, E, NB);
    csr_k<<<NB, 256, 0, stream>>>(ebuf, bcur, offS, offE, csr, dinv, N);

    // Layer 1
    gemm64_scale_k<<<(N + 255) / 256, 256, 0, stream>>>(x, W1, dinv, bufA, N);
    agg_k<0><<<(N + 3) / 4, 256, 0, stream>>>(bufA, csr, offS, offE, dinv, b1,
                                              nullptr, nullptr, bufB, N);
    // Layer 2 + fused linear head
    gemm64_scale_k<<<(N + 255) / 256, 256, 0, stream>>>(bufB, W2, dinv, bufA, N);
    agg_k<1><<<(N + 3) / 4, 256, 0, stream>>>(bufA, csr, offS, offE, dinv, b2,
                                              Wl, bl, (float*)d_out, N);
}

// Round 8
// 356.748 us; speedup vs baseline: 1.8256x; 1.2521x over previous
//
#include <hip/hip_runtime.h>
#include <hip/hip_fp16.h>

// ---------------------------------------------------------------------------
// 2-layer GCN on MI355X.
//   out[i] = relu(dinv[i]*(G[i] + sum_{s in in(i)} G[s]) + b), G = rowscale(X@W,dinv)
// G stored in fp16 (128 B rows) -> halves the random-gather fill traffic.
// Preprocessing:
//   bfill2_k: 8192-edge blocks; LDS histogram over 782 dst>>7 buckets, block
//             scan, one global atomic per (block,bucket) chunk reserve,
//             block-local counting sort in LDS, coalesced chunk write-out.
//   csr_k:    block-per-bucket, LDS-staged segment, count+scan -> per-node
//             offS/offE/dinv, single reorder pass (src-band ordering removed:
//             measured null in R7).
// Aggregation: wave-per-node, quad-per-edge 8B fp16 gather, f32 accum,
// butterfly merge. Final linear head fused into layer-2 aggregation.
// ---------------------------------------------------------------------------

#define EBLK 8192  // edges per bucketing block
#define CAP 6144   // bucket capacity (mean 4092, +32 sigma)

__global__ __launch_bounds__(256) void bfill2_k(const int* __restrict__ src,
                                                const int* __restrict__ dst,
                                                int* __restrict__ bcur,
                                                int* __restrict__ ebuf, int E) {
    __shared__ int h[1024];
    __shared__ int loff[1025];
    __shared__ int cur[1024];
    __shared__ int bbase[1024];
    __shared__ int lsum[256];
    __shared__ int sbuf[EBLK];  // 32 KiB
    int t = threadIdx.x;
#pragma unroll
    for (int j = 0; j < 4; j++) h[t + 256 * j] = 0;
    __syncthreads();
    int base = blockIdx.x * EBLK;
    int nloc = E - base; if (nloc > EBLK) nloc = EBLK;
    // 1. histogram over dst buckets
#pragma unroll 4
    for (int r = 0; r < 32; r++) {
        int i = r * 256 + t;
        if (i < nloc) atomicAdd(&h[((unsigned)dst[base + i]) >> 7], 1);
    }
    __syncthreads();
    // 2. exclusive scan of 1024 counts (4/thread + 256-scan)
    int t4 = t * 4;
    int a0 = h[t4], a1 = h[t4 + 1], a2 = h[t4 + 2], a3 = h[t4 + 3];
    lsum[t] = a0 + a1 + a2 + a3;
    __syncthreads();
    for (int d = 1; d < 256; d <<= 1) {
        int v = (t >= d) ? lsum[t - d] : 0;
        __syncthreads();
        lsum[t] += v;
        __syncthreads();
    }
    int excl = (t > 0) ? lsum[t - 1] : 0;
    loff[t4] = excl;                 cur[t4] = excl;
    loff[t4 + 1] = excl + a0;        cur[t4 + 1] = loff[t4 + 1];
    loff[t4 + 2] = excl + a0 + a1;   cur[t4 + 2] = loff[t4 + 2];
    loff[t4 + 3] = excl + a0 + a1 + a2; cur[t4 + 3] = loff[t4 + 3];
    if (t == 255) loff[1024] = lsum[255];
    // 3. reserve global chunk per non-empty bucket
#pragma unroll
    for (int j = 0; j < 4; j++) {
        int b = t + 256 * j;
        if (h[b]) bbase[b] = atomicAdd(&bcur[b], h[b]);
    }
    __syncthreads();
    // 4. counting-sort scatter into LDS
#pragma unroll 4
    for (int r = 0; r < 32; r++) {
        int i = r * 256 + t;
        if (i < nloc) {
            int d = dst[base + i];
            int b = ((unsigned)d) >> 7;
            int pos = atomicAdd(&cur[b], 1);
            sbuf[pos] = src[base + i] | ((d & 127) << 20);
        }
    }
    __syncthreads();
    // 5. coalesced write-out (bucket of entry i via binary search in loff)
#pragma unroll 4
    for (int r = 0; r < 32; r++) {
        int i = r * 256 + t;
        if (i < nloc) {
            int lo = 0, hi = 1024;
            while (hi - lo > 1) {
                int mid = (lo + hi) >> 1;
                if (loff[mid] <= i) lo = mid; else hi = mid;
            }
            int idx = bbase[lo] + (i - loff[lo]);
            if (idx < CAP) ebuf[(size_t)lo * CAP + idx] = sbuf[i];
        }
    }
}

// Block-per-bucket: per-node offS/offE/dinv + single-pass reorder into the
// bucket's fixed csr window.
__global__ __launch_bounds__(256) void csr_k(const int* __restrict__ ebuf,
                                             const int* __restrict__ bcur,
                                             int* __restrict__ offS,
                                             int* __restrict__ offE,
                                             int* __restrict__ csr,
                                             float* __restrict__ dinv, int n) {
    __shared__ int seg[CAP];  // 24 KiB
    __shared__ int cnt[128];
    __shared__ int pre[128];
    __shared__ int cur[128];
    int t = threadIdx.x;
    if (t < 128) cnt[t] = 0;
    int b = blockIdx.x;
    int len = bcur[b]; if (len > CAP) len = CAP;
    int s0 = b * CAP;
    for (int i = t; i < len; i += 256) seg[i] = ebuf[s0 + i];
    __syncthreads();
    for (int i = t; i < len; i += 256)
        atomicAdd(&cnt[((unsigned)seg[i]) >> 20], 1);
    __syncthreads();
    if (t < 128) pre[t] = cnt[t];
    __syncthreads();
    for (int d = 1; d < 128; d <<= 1) {
        int v = (t >= d && t < 128) ? pre[t - d] : 0;
        __syncthreads();
        if (t < 128) pre[t] += v;
        __syncthreads();
    }
    if (t < 128) {
        int excl = pre[t] - cnt[t];
        cur[t] = excl;
        int gn = (b << 7) + t;
        if (gn < n) {
            offS[gn] = s0 + excl;
            offE[gn] = s0 + excl + cnt[t];
            dinv[gn] = rsqrtf((float)(cnt[t] + 1));
        }
    }
    __syncthreads();
    for (int i = t; i < len; i += 256) {
        int v = seg[i];
        int rk = atomicAdd(&cur[((unsigned)v) >> 20], 1);
        csr[s0 + rk] = v & 0xFFFFF;
    }
}

// G[r][:] = fp16( dinv[r] * (X[r][:] @ W) ).  Thread-per-row, W in LDS.
__global__ __launch_bounds__(256) void gemm64h_k(
    const float* __restrict__ X, const float* __restrict__ W,
    const float* __restrict__ dinv, __half* __restrict__ G, int n) {
    __shared__ float wl[64 * 64];
    int t = threadIdx.x;
#pragma unroll
    for (int u = 0; u < 16; u++) wl[t + 256 * u] = W[t + 256 * u];
    __syncthreads();
    int r = blockIdx.x * 256 + t;
    if (r >= n) return;

    const float4* xp = (const float4*)(X + (size_t)r * 64);
    float4 acc[16];
#pragma unroll
    for (int j = 0; j < 16; j++) acc[j] = make_float4(0.f, 0.f, 0.f, 0.f);

    for (int i = 0; i < 16; i++) {
        float4 xv = xp[i];
#pragma unroll
        for (int c = 0; c < 4; c++) {
            float xk = (c == 0) ? xv.x : (c == 1) ? xv.y : (c == 2) ? xv.z : xv.w;
            const float4* wr = (const float4*)(wl + (i * 4 + c) * 64);
#pragma unroll
            for (int j = 0; j < 16; j++) {
                float4 wv = wr[j];
                acc[j].x = fmaf(xk, wv.x, acc[j].x);
                acc[j].y = fmaf(xk, wv.y, acc[j].y);
                acc[j].z = fmaf(xk, wv.z, acc[j].z);
                acc[j].w = fmaf(xk, wv.w, acc[j].w);
            }
        }
    }
    float sc = dinv[r];
    __half2* gp = (__half2*)(G + (size_t)r * 64);
#pragma unroll
    for (int j = 0; j < 16; j++) {
        float4 v = acc[j];
        gp[2 * j]     = __floats2half2_rn(v.x * sc, v.y * sc);
        gp[2 * j + 1] = __floats2half2_rn(v.z * sc, v.w * sc);
    }
}

__device__ inline float4 ld4(const float* p) { return *(const float4*)p; }
__device__ inline void add4(float4& a, float4 g) {
    a.x += g.x; a.y += g.y; a.z += g.z; a.w += g.w;
}
__device__ inline void bfly4(float4& a, int m) {
    a.x += __shfl_xor(a.x, m);
    a.y += __shfl_xor(a.y, m);
    a.z += __shfl_xor(a.z, m);
    a.w += __shfl_xor(a.w, m);
}
// 8-byte fp16 gather (4 features) -> f32
__device__ inline float4 ldh4(const __half* __restrict__ G, int row, int fo) {
    float2 raw = *(const float2*)(G + (size_t)row * 64 + fo);
    __half2 h0 = *reinterpret_cast<const __half2*>(&raw.x);
    __half2 h1 = *reinterpret_cast<const __half2*>(&raw.y);
    float2 f0 = __half22float2(h0);
    float2 f1 = __half22float2(h1);
    return make_float4(f0.x, f0.y, f1.x, f1.y);
}

// Wave-per-node aggregation, quad-per-edge fp16 gather (8 B/lane).
// lane = 16*q + fcol; quad q handles edge u+q; 16 lanes x 8B = 128B row.
// FINAL=0: Out[node][:] = relu(dinv*acc + bias)   (f32)
// FINAL=1: Out[node] = relu(...) . Wl + bl
template <int FINAL>
__global__ __launch_bounds__(256) void agg_k(
    const __half* __restrict__ G, const int* __restrict__ csr,
    const int* __restrict__ offS, const int* __restrict__ offE,
    const float* __restrict__ dinv, const float* __restrict__ bias,
    const float* __restrict__ Wl, const float* __restrict__ bl,
    float* __restrict__ Out, int n) {
    int lane = threadIdx.x & 63;
    int wid = threadIdx.x >> 6;
    int node = blockIdx.x * 4 + wid;
    if (node >= n) return;

    int q = lane >> 4;
    int fl = (lane & 15) << 2;  // feature base for this lane's 4 features

    float4 a = make_float4(0.f, 0.f, 0.f, 0.f);
    if (q == 0) a = ldh4(G, node, fl);  // self-loop term

    int s0 = offS[node], s1 = offE[node];
    for (int base = s0; base < s1; base += 64) {
        int m = s1 - base;
        if (m > 64) m = 64;
        int e = (lane < m) ? csr[base + lane] : 0;
        int u = 0;
        for (; u + 16 <= m; u += 16) {
            int e0 = __shfl(e, u + q);
            int e1 = __shfl(e, u + 4 + q);
            int e2 = __shfl(e, u + 8 + q);
            int e3 = __shfl(e, u + 12 + q);
            float4 g0 = ldh4(G, e0, fl);
            float4 g1 = ldh4(G, e1, fl);
            float4 g2 = ldh4(G, e2, fl);
            float4 g3 = ldh4(G, e3, fl);
            add4(a, g0); add4(a, g1); add4(a, g2); add4(a, g3);
        }
        for (; u + 4 <= m; u += 4) {
            int e0 = __shfl(e, u + q);
            add4(a, ldh4(G, e0, fl));
        }
        if (u < m) {  // tail of 1..3 edges (u, m wave-uniform)
            int e0 = __shfl(e, (u + q < m) ? (u + q) : 0);
            if (u + q < m) add4(a, ldh4(G, e0, fl));
        }
    }
    // merge quads: butterfly across lane bits 4,5
    bfly4(a, 16);
    bfly4(a, 32);

    float di = dinv[node];
    float4 bv = ld4(bias + fl);
    float4 v;
    v.x = fmaxf(fmaf(di, a.x, bv.x), 0.f);
    v.y = fmaxf(fmaf(di, a.y, bv.y), 0.f);
    v.z = fmaxf(fmaf(di, a.z, bv.z), 0.f);
    v.w = fmaxf(fmaf(di, a.w, bv.w), 0.f);

    if (FINAL) {
        float4 wv = ld4(Wl + fl);
        float p = v.x * wv.x + v.y * wv.y + v.z * wv.z + v.w * wv.w;
#pragma unroll
        for (int d = 8; d > 0; d >>= 1) p += __shfl_xor(p, d);
        if (lane == 0) Out[node] = p + bl[0];
    } else {
        if (q == 0) *(float4*)(Out + (size_t)node * 64 + fl) = v;
    }
}

extern "C" void kernel_launch(void* const* d_in, const int* in_sizes, int n_in,
                              void* d_out, int out_size, void* d_ws, size_t ws_size,
                              hipStream_t stream) {
    const float* x  = (const float*)d_in[0];
    const int*   ei = (const int*)d_in[1];
    const float* W1 = (const float*)d_in[2];
    const float* b1 = (const float*)d_in[3];
    const float* W2 = (const float*)d_in[4];
    const float* b2 = (const float*)d_in[5];
    const float* Wl = (const float*)d_in[6];
    const float* bl = (const float*)d_in[7];

    const int N = in_sizes[0] / 64;
    const int E = in_sizes[1] / 2;
    const int* src = ei;
    const int* dst = ei + E;
    const int NB = (N + 127) >> 7;         // 782 buckets (<=1024 assumed)
    const int FB = (E + EBLK - 1) / EBLK;  // 391

    char* w = (char*)d_ws;
    size_t o = 0;
    auto take = [&](size_t bytes) {
        void* p = w + o;
        o = (o + bytes + 255) & ~(size_t)255;
        return p;
    };
    int*    bcur = (int*)take((size_t)NB * 4);
    float*  dinv = (float*)take((size_t)N * 4);
    int*    offS = (int*)take((size_t)N * 4);
    int*    offE = (int*)take((size_t)N * 4);
    int*    csr  = (int*)take((size_t)NB * CAP * 4);   // 19.2 MB (holey)
    int*    ebuf = (int*)take((size_t)NB * CAP * 4);   // 19.2 MB
    __half* G    = (__half*)take((size_t)N * 64 * 2);  // 12.8 MB (fp16)
    float*  h1   = (float*)take((size_t)N * 64 * 4);   // 25.6 MB

    hipMemsetAsync(bcur, 0, (size_t)NB * 4, stream);
    bfill2_k<<<FB, 256, 0, stream>>>(src, dst, bcur, ebuf, E);
    csr_k<<<NB, 256, 0, stream>>>(ebuf, bcur, offS, offE, csr, dinv, N);

    // Layer 1
    gemm64h_k<<<(N + 255) / 256, 256, 0, stream>>>(x, W1, dinv, G, N);
    agg_k<0><<<(N + 3) / 4, 256, 0, stream>>>(G, csr, offS, offE, dinv, b1,
                                              nullptr, nullptr, h1, N);
    // Layer 2 + fused linear head
    gemm64h_k<<<(N + 255) / 256, 256, 0, stream>>>(h1, W2, dinv, G, N);
    agg_k<1><<<(N + 3) / 4, 256, 0, stream>>>(G, csr, offS, offE, dinv, b2,
                                              Wl, bl, (float*)d_out, N);
}

// Round 14
// 354.210 us; speedup vs baseline: 1.8387x; 1.0072x over previous
//
#include <hip/hip_runtime.h>
#include <hip/hip_fp16.h>

// ---------------------------------------------------------------------------
// 2-layer GCN on MI355X.
//   out[i] = relu(dinv[i]*(G[i] + sum_{s in in(i)} G[s]) + b), G = rowscale(X@W,dinv)
// G and the inter-layer activation h1 stored fp16.
// Preprocessing:
//   bfill2_k: R8-proven 256-thr version. LDS histogram over 1024 dst>>7
//             buckets, chunk reserve (1 global atomic per block,bucket), LDS
//             counting sort, coalesced chunk write-out.
//   csr2_k:   half-bucket (64-node) blocks, no LDS staging (ebuf re-read from
//             L2): count+scan -> offS/offE/dinv, reorder own half into csr.
// Aggregation: wave-per-node, quad-per-edge 8B fp16 gather, f32 accum,
// butterfly merge. Final linear head fused into layer-2 aggregation.
// ---------------------------------------------------------------------------

#define EBLK 8192  // edges per bucketing block
#define CAP 6144   // bucket capacity (mean 4092, +32 sigma)

__global__ __launch_bounds__(256) void bfill2_k(const int* __restrict__ src,
                                                const int* __restrict__ dst,
                                                int* __restrict__ bcur,
                                                int* __restrict__ ebuf, int E) {
    __shared__ int h[1024];
    __shared__ int loff[1025];
    __shared__ int cur[1024];
    __shared__ int bbase[1024];
    __shared__ int lsum[256];
    __shared__ int sbuf[EBLK];  // 32 KiB
    int t = threadIdx.x;
#pragma unroll
    for (int j = 0; j < 4; j++) h[t + 256 * j] = 0;
    __syncthreads();
    int base = blockIdx.x * EBLK;
    int nloc = E - base; if (nloc > EBLK) nloc = EBLK;
    // 1. histogram over dst buckets
#pragma unroll 4
    for (int r = 0; r < 32; r++) {
        int i = r * 256 + t;
        if (i < nloc) atomicAdd(&h[((unsigned)dst[base + i]) >> 7], 1);
    }
    __syncthreads();
    // 2. exclusive scan of 1024 counts (4/thread + 256-scan)
    int t4 = t * 4;
    int a0 = h[t4], a1 = h[t4 + 1], a2 = h[t4 + 2], a3 = h[t4 + 3];
    lsum[t] = a0 + a1 + a2 + a3;
    __syncthreads();
    for (int d = 1; d < 256; d <<= 1) {
        int v = (t >= d) ? lsum[t - d] : 0;
        __syncthreads();
        lsum[t] += v;
        __syncthreads();
    }
    int excl = (t > 0) ? lsum[t - 1] : 0;
    loff[t4] = excl;                 cur[t4] = excl;
    loff[t4 + 1] = excl + a0;        cur[t4 + 1] = loff[t4 + 1];
    loff[t4 + 2] = excl + a0 + a1;   cur[t4 + 2] = loff[t4 + 2];
    loff[t4 + 3] = excl + a0 + a1 + a2; cur[t4 + 3] = loff[t4 + 3];
    if (t == 255) loff[1024] = lsum[255];
    // 3. reserve global chunk per non-empty bucket
#pragma unroll
    for (int j = 0; j < 4; j++) {
        int b = t + 256 * j;
        if (h[b]) bbase[b] = atomicAdd(&bcur[b], h[b]);
    }
    __syncthreads();
    // 4. counting-sort scatter into LDS
#pragma unroll 4
    for (int r = 0; r < 32; r++) {
        int i = r * 256 + t;
        if (i < nloc) {
            int d = dst[base + i];
            int b = ((unsigned)d) >> 7;
            int pos = atomicAdd(&cur[b], 1);
            sbuf[pos] = src[base + i] | ((d & 127) << 20);
        }
    }
    __syncthreads();
    // 5. coalesced write-out (bucket of entry i via binary search in loff)
#pragma unroll 4
    for (int r = 0; r < 32; r++) {
        int i = r * 256 + t;
        if (i < nloc) {
            int lo = 0, hi = 1024;
            while (hi - lo > 1) {
                int mid = (lo + hi) >> 1;
                if (loff[mid] <= i) lo = mid; else hi = mid;
            }
            int idx = bbase[lo] + (i - loff[lo]);
            if (idx < CAP) ebuf[(size_t)lo * CAP + idx] = sbuf[i];
        }
    }
}

// Half-bucket blocks (64 nodes each): count all, scan, write own half's
// offS/offE/dinv, reorder own half's edges. No LDS staging (ebuf L2-hot).
__global__ __launch_bounds__(256) void csr2_k(const int* __restrict__ ebuf,
                                              const int* __restrict__ bcur,
                                              int* __restrict__ offS,
                                              int* __restrict__ offE,
                                              int* __restrict__ csr,
                                              float* __restrict__ dinv, int n) {
    __shared__ int cnt[128];
    __shared__ int pre[128];
    __shared__ int cur[64];
    int t = threadIdx.x;
    if (t < 128) cnt[t] = 0;
    __syncthreads();
    int b2 = blockIdx.x;
    int b = b2 >> 1, half = b2 & 1;
    int len = bcur[b]; if (len > CAP) len = CAP;
    int s0 = b * CAP;
    const int* seg = ebuf + s0;
    for (int i = t; i < len; i += 256)
        atomicAdd(&cnt[((unsigned)seg[i]) >> 20], 1);
    __syncthreads();
    if (t < 128) pre[t] = cnt[t];
    __syncthreads();
    for (int d = 1; d < 128; d <<= 1) {
        int v = (t >= d && t < 128) ? pre[t - d] : 0;
        __syncthreads();
        if (t < 128) pre[t] += v;
        __syncthreads();
    }
    if (t < 64) {
        int l = half * 64 + t;
        int excl = pre[l] - cnt[l];
        cur[t] = excl;
        int gn = (b << 7) + l;
        if (gn < n) {
            offS[gn] = s0 + excl;
            offE[gn] = s0 + pre[l];
            dinv[gn] = rsqrtf((float)(cnt[l] + 1));
        }
    }
    __syncthreads();
    for (int i = t; i < len; i += 256) {
        int v = seg[i];
        int l = ((unsigned)v) >> 20;
        if ((l >> 6) == half) {
            int rk = atomicAdd(&cur[l & 63], 1);
            csr[s0 + rk] = v & 0xFFFFF;
        }
    }
}

// load 4 consecutive features of row r, group i (features 4i..4i+3), as f32
__device__ inline float4 ldg4(const float* __restrict__ X, int r, int i) {
    return ((const float4*)(X + (size_t)r * 64))[i];
}
__device__ inline float4 ldg4(const __half* __restrict__ X, int r, int i) {
    float2 raw = ((const float2*)(X + (size_t)r * 64))[i];
    __half2 h0 = *reinterpret_cast<const __half2*>(&raw.x);
    __half2 h1 = *reinterpret_cast<const __half2*>(&raw.y);
    float2 f0 = __half22float2(h0);
    float2 f1 = __half22float2(h1);
    return make_float4(f0.x, f0.y, f1.x, f1.y);
}

// G[r][:] = fp16( dinv[r] * (X[r][:] @ W) ).  Thread-per-row, W in LDS.
template <typename T>
__global__ __launch_bounds__(256) void gemm64h_k(
    const T* __restrict__ X, const float* __restrict__ W,
    const float* __restrict__ dinv, __half* __restrict__ G, int n) {
    __shared__ float wl[64 * 64];
    int t = threadIdx.x;
#pragma unroll
    for (int u = 0; u < 16; u++) wl[t + 256 * u] = W[t + 256 * u];
    __syncthreads();
    int r = blockIdx.x * 256 + t;
    if (r >= n) return;

    float4 acc[16];
#pragma unroll
    for (int j = 0; j < 16; j++) acc[j] = make_float4(0.f, 0.f, 0.f, 0.f);

    for (int i = 0; i < 16; i++) {
        float4 xv = ldg4(X, r, i);
#pragma unroll
        for (int c = 0; c < 4; c++) {
            float xk = (c == 0) ? xv.x : (c == 1) ? xv.y : (c == 2) ? xv.z : xv.w;
            const float4* wr = (const float4*)(wl + (i * 4 + c) * 64);
#pragma unroll
            for (int j = 0; j < 16; j++) {
                float4 wv = wr[j];
                acc[j].x = fmaf(xk, wv.x, acc[j].x);
                acc[j].y = fmaf(xk, wv.y, acc[j].y);
                acc[j].z = fmaf(xk, wv.z, acc[j].z);
                acc[j].w = fmaf(xk, wv.w, acc[j].w);
            }
        }
    }
    float sc = dinv[r];
    __half2* gp = (__half2*)(G + (size_t)r * 64);
#pragma unroll
    for (int j = 0; j < 16; j++) {
        float4 v = acc[j];
        gp[2 * j]     = __floats2half2_rn(v.x * sc, v.y * sc);
        gp[2 * j + 1] = __floats2half2_rn(v.z * sc, v.w * sc);
    }
}

__device__ inline float4 ld4(const float* p) { return *(const float4*)p; }
__device__ inline void add4(float4& a, float4 g) {
    a.x += g.x; a.y += g.y; a.z += g.z; a.w += g.w;
}
__device__ inline void bfly4(float4& a, int m) {
    a.x += __shfl_xor(a.x, m);
    a.y += __shfl_xor(a.y, m);
    a.z += __shfl_xor(a.z, m);
    a.w += __shfl_xor(a.w, m);
}
// 8-byte fp16 gather (4 features) -> f32
__device__ inline float4 ldh4(const __half* __restrict__ G, int row, int fo) {
    float2 raw = *(const float2*)(G + (size_t)row * 64 + fo);
    __half2 h0 = *reinterpret_cast<const __half2*>(&raw.x);
    __half2 h1 = *reinterpret_cast<const __half2*>(&raw.y);
    float2 f0 = __half22float2(h0);
    float2 f1 = __half22float2(h1);
    return make_float4(f0.x, f0.y, f1.x, f1.y);
}

// Wave-per-node aggregation, quad-per-edge fp16 gather (8 B/lane).
// lane = 16*q + fcol; quad q handles edge u+q; 16 lanes x 8B = 128B row.
// FINAL=0: Out = __half h1[node][:] = relu(dinv*acc + bias)
// FINAL=1: Out = float d_out[node] = relu(...) . Wl + bl
template <int FINAL>
__global__ __launch_bounds__(256) void agg_k(
    const __half* __restrict__ G, const int* __restrict__ csr,
    const int* __restrict__ offS, const int* __restrict__ offE,
    const float* __restrict__ dinv, const float* __restrict__ bias,
    const float* __restrict__ Wl, const float* __restrict__ bl,
    void* __restrict__ OutP, int n) {
    int lane = threadIdx.x & 63;
    int wid = threadIdx.x >> 6;
    int node = blockIdx.x * 4 + wid;
    if (node >= n) return;

    int q = lane >> 4;
    int fl = (lane & 15) << 2;  // feature base for this lane's 4 features

    float4 a = make_float4(0.f, 0.f, 0.f, 0.f);
    if (q == 0) a = ldh4(G, node, fl);  // self-loop term

    int s0 = offS[node], s1 = offE[node];
    for (int base = s0; base < s1; base += 64) {
        int m = s1 - base;
        if (m > 64) m = 64;
        int e = (lane < m) ? csr[base + lane] : 0;
        int u = 0;
        for (; u + 16 <= m; u += 16) {
            int e0 = __shfl(e, u + q);
            int e1 = __shfl(e, u + 4 + q);
            int e2 = __shfl(e, u + 8 + q);
            int e3 = __shfl(e, u + 12 + q);
            float4 g0 = ldh4(G, e0, fl);
            float4 g1 = ldh4(G, e1, fl);
            float4 g2 = ldh4(G, e2, fl);
            float4 g3 = ldh4(G, e3, fl);
            add4(a, g0); add4(a, g1); add4(a, g2); add4(a, g3);
        }
        for (; u + 4 <= m; u += 4) {
            int e0 = __shfl(e, u + q);
            add4(a, ldh4(G, e0, fl));
        }
        if (u < m) {  // tail of 1..3 edges (u, m wave-uniform)
            int e0 = __shfl(e, (u + q < m) ? (u + q) : 0);
            if (u + q < m) add4(a, ldh4(G, e0, fl));
        }
    }
    // merge quads: butterfly across lane bits 4,5
    bfly4(a, 16);
    bfly4(a, 32);

    float di = dinv[node];
    float4 bv = ld4(bias + fl);
    float4 v;
    v.x = fmaxf(fmaf(di, a.x, bv.x), 0.f);
    v.y = fmaxf(fmaf(di, a.y, bv.y), 0.f);
    v.z = fmaxf(fmaf(di, a.z, bv.z), 0.f);
    v.w = fmaxf(fmaf(di, a.w, bv.w), 0.f);

    if (FINAL) {
        float4 wv = ld4(Wl + fl);
        float p = v.x * wv.x + v.y * wv.y + v.z * wv.z + v.w * wv.w;
#pragma unroll
        for (int d = 8; d > 0; d >>= 1) p += __shfl_xor(p, d);
        if (lane == 0) ((float*)OutP)[node] = p + bl[0];
    } else {
        if (q == 0) {
            __half2 p0 = __floats2half2_rn(v.x, v.y);
            __half2 p1 = __floats2half2_rn(v.z, v.w);
            float2 packed;
            packed.x = *reinterpret_cast<float*>(&p0);
            packed.y = *reinterpret_cast<float*>(&p1);
            *(float2*)((__half*)OutP + (size_t)node * 64 + fl) = packed;
        }
    }
}

extern "C" void kernel_launch(void* const* d_in, const int* in_sizes, int n_in,
                              void* d_out, int out_size, void* d_ws, size_t ws_size,
                              hipStream_t stream) {
    const float* x  = (const float*)d_in[0];
    const int*   ei = (const int*)d_in[1];
    const float* W1 = (const float*)d_in[2];
    const float* b1 = (const float*)d_in[3];
    const float* W2 = (const float*)d_in[4];
    const float* b2 = (const float*)d_in[5];
    const float* Wl = (const float*)d_in[6];
    const float* bl = (const float*)d_in[7];

    const int N = in_sizes[0] / 64;
    const int E = in_sizes[1] / 2;
    const int* src = ei;
    const int* dst = ei + E;
    const int NB = (N + 127) >> 7;         // 782 buckets (<=1024 assumed)
    const int FB = (E + EBLK - 1) / EBLK;  // 391

    char* w = (char*)d_ws;
    size_t o = 0;
    auto take = [&](size_t bytes) {
        void* p = w + o;
        o = (o + bytes + 255) & ~(size_t)255;
        return p;
    };
    int*    bcur = (int*)take((size_t)NB * 4);
    float*  dinv = (float*)take((size_t)N * 4);
    int*    offS = (int*)take((size_t)N * 4);
    int*    offE = (int*)take((size_t)N * 4);
    int*    csr  = (int*)take((size_t)NB * CAP * 4);   // 19.2 MB (holey)
    int*    ebuf = (int*)take((size_t)NB * CAP * 4);   // 19.2 MB
    __half* G    = (__half*)take((size_t)N * 64 * 2);  // 12.8 MB
    __half* h1   = (__half*)take((size_t)N * 64 * 2);  // 12.8 MB

    hipMemsetAsync(bcur, 0, (size_t)NB * 4, stream);
    bfill2_k<<<FB, 256, 0, stream>>>(src, dst, bcur, ebuf, E);
    csr2_k<<<2 * NB, 256, 0, stream>>>(ebuf, bcur, offS, offE, csr, dinv, N);

    // Layer 1
    gemm64h_k<float><<<(N + 255) / 256, 256, 0, stream>>>(x, W1, dinv, G, N);
    agg_k<0><<<(N + 3) / 4, 256, 0, stream>>>(G, csr, offS, offE, dinv, b1,
                                              nullptr, nullptr, h1, N);
    // Layer 2 + fused linear head
    gemm64h_k<__half><<<(N + 255) / 256, 256, 0, stream>>>(h1, W2, dinv, G, N);
    agg_k<1><<<(N + 3) / 4, 256, 0, stream>>>(G, csr, offS, offE, dinv, b2,
                                              Wl, bl, d_out, N);
}

// Round 15
// 344.000 us; speedup vs baseline: 1.8933x; 1.0297x over previous
//
#include <hip/hip_runtime.h>
#include <hip/hip_fp16.h>

// ---------------------------------------------------------------------------
// 2-layer GCN on MI355X.
//   out[i] = relu(dinv[i]*(G[i] + sum_{s in in(i)} G[s]) + b), G = rowscale(X@W,dinv)
// G and the inter-layer activation h1 stored fp16.
// Preprocessing:
//   bfill_k:  256-thr, 12KB LDS (13 blocks/CU). LDS histogram over 1024
//             dst>>7 buckets, one global atomic per (block,bucket) chunk
//             reserve, direct ranked write into the bucket's fixed-CAP window.
//             (R8's counting-sort variant: 50KB LDS, 3 blocks/CU, 72us --
//             write coalescing not worth the occupancy loss at 6% HBM.)
//   csr2_k:   half-bucket (64-node) blocks, no LDS staging (ebuf L2-hot):
//             count+scan -> offS/offE/dinv, reorder own half into csr.
// Aggregation: wave-per-node, quad-per-edge 8B fp16 gather, f32 accum,
// butterfly merge. Final linear head fused into layer-2 aggregation.
// ---------------------------------------------------------------------------

#define EBLK 8192  // edges per bucketing block
#define CAP 6144   // bucket capacity (mean 4092, +32 sigma)

__global__ __launch_bounds__(256) void bfill_k(const int* __restrict__ src,
                                               const int* __restrict__ dst,
                                               int* __restrict__ bcur,
                                               int* __restrict__ ebuf, int E) {
    __shared__ int h[1024];      // histogram, then per-bucket rank cursor
    __shared__ int bbase[1024];  // reserved chunk base in bucket window
    int t = threadIdx.x;
#pragma unroll
    for (int j = 0; j < 4; j++) h[t + 256 * j] = 0;
    __syncthreads();
    int base = blockIdx.x * EBLK;
    int nloc = E - base; if (nloc > EBLK) nloc = EBLK;
    // 1. histogram over dst buckets
#pragma unroll 4
    for (int r = 0; r < 32; r++) {
        int i = r * 256 + t;
        if (i < nloc) atomicAdd(&h[((unsigned)dst[base + i]) >> 7], 1);
    }
    __syncthreads();
    // 2. reserve global chunk per non-empty bucket; reset cursor
#pragma unroll
    for (int j = 0; j < 4; j++) {
        int b = t + 256 * j;
        if (h[b]) bbase[b] = atomicAdd(&bcur[b], h[b]);
        h[b] = 0;
    }
    __syncthreads();
    // 3. ranked direct write (runs of ~10 contiguous ints per bucket chunk)
#pragma unroll 4
    for (int r = 0; r < 32; r++) {
        int i = r * 256 + t;
        if (i < nloc) {
            int d = dst[base + i];
            int b = ((unsigned)d) >> 7;
            int rk = atomicAdd(&h[b], 1);
            int idx = bbase[b] + rk;
            if (idx < CAP) ebuf[(size_t)b * CAP + idx] = src[base + i] | ((d & 127) << 20);
        }
    }
}

// Half-bucket blocks (64 nodes each): count all, scan, write own half's
// offS/offE/dinv, reorder own half's edges. No LDS staging (ebuf L2-hot).
__global__ __launch_bounds__(256) void csr2_k(const int* __restrict__ ebuf,
                                              const int* __restrict__ bcur,
                                              int* __restrict__ offS,
                                              int* __restrict__ offE,
                                              int* __restrict__ csr,
                                              float* __restrict__ dinv, int n) {
    __shared__ int cnt[128];
    __shared__ int pre[128];
    __shared__ int cur[64];
    int t = threadIdx.x;
    if (t < 128) cnt[t] = 0;
    __syncthreads();
    int b2 = blockIdx.x;
    int b = b2 >> 1, half = b2 & 1;
    int len = bcur[b]; if (len > CAP) len = CAP;
    int s0 = b * CAP;
    const int* seg = ebuf + s0;
    for (int i = t; i < len; i += 256)
        atomicAdd(&cnt[((unsigned)seg[i]) >> 20], 1);
    __syncthreads();
    if (t < 128) pre[t] = cnt[t];
    __syncthreads();
    for (int d = 1; d < 128; d <<= 1) {
        int v = (t >= d && t < 128) ? pre[t - d] : 0;
        __syncthreads();
        if (t < 128) pre[t] += v;
        __syncthreads();
    }
    if (t < 64) {
        int l = half * 64 + t;
        int excl = pre[l] - cnt[l];
        cur[t] = excl;
        int gn = (b << 7) + l;
        if (gn < n) {
            offS[gn] = s0 + excl;
            offE[gn] = s0 + pre[l];
            dinv[gn] = rsqrtf((float)(cnt[l] + 1));
        }
    }
    __syncthreads();
    for (int i = t; i < len; i += 256) {
        int v = seg[i];
        int l = ((unsigned)v) >> 20;
        if ((l >> 6) == half) {
            int rk = atomicAdd(&cur[l & 63], 1);
            csr[s0 + rk] = v & 0xFFFFF;
        }
    }
}

// load 4 consecutive features of row r, group i (features 4i..4i+3), as f32
__device__ inline float4 ldg4(const float* __restrict__ X, int r, int i) {
    return ((const float4*)(X + (size_t)r * 64))[i];
}
__device__ inline float4 ldg4(const __half* __restrict__ X, int r, int i) {
    float2 raw = ((const float2*)(X + (size_t)r * 64))[i];
    __half2 h0 = *reinterpret_cast<const __half2*>(&raw.x);
    __half2 h1 = *reinterpret_cast<const __half2*>(&raw.y);
    float2 f0 = __half22float2(h0);
    float2 f1 = __half22float2(h1);
    return make_float4(f0.x, f0.y, f1.x, f1.y);
}

// G[r][:] = fp16( dinv[r] * (X[r][:] @ W) ).  Thread-per-row, W in LDS.
template <typename T>
__global__ __launch_bounds__(256) void gemm64h_k(
    const T* __restrict__ X, const float* __restrict__ W,
    const float* __restrict__ dinv, __half* __restrict__ G, int n) {
    __shared__ float wl[64 * 64];
    int t = threadIdx.x;
#pragma unroll
    for (int u = 0; u < 16; u++) wl[t + 256 * u] = W[t + 256 * u];
    __syncthreads();
    int r = blockIdx.x * 256 + t;
    if (r >= n) return;

    float4 acc[16];
#pragma unroll
    for (int j = 0; j < 16; j++) acc[j] = make_float4(0.f, 0.f, 0.f, 0.f);

    for (int i = 0; i < 16; i++) {
        float4 xv = ldg4(X, r, i);
#pragma unroll
        for (int c = 0; c < 4; c++) {
            float xk = (c == 0) ? xv.x : (c == 1) ? xv.y : (c == 2) ? xv.z : xv.w;
            const float4* wr = (const float4*)(wl + (i * 4 + c) * 64);
#pragma unroll
            for (int j = 0; j < 16; j++) {
                float4 wv = wr[j];
                acc[j].x = fmaf(xk, wv.x, acc[j].x);
                acc[j].y = fmaf(xk, wv.y, acc[j].y);
                acc[j].z = fmaf(xk, wv.z, acc[j].z);
                acc[j].w = fmaf(xk, wv.w, acc[j].w);
            }
        }
    }
    float sc = dinv[r];
    __half2* gp = (__half2*)(G + (size_t)r * 64);
#pragma unroll
    for (int j = 0; j < 16; j++) {
        float4 v = acc[j];
        gp[2 * j]     = __floats2half2_rn(v.x * sc, v.y * sc);
        gp[2 * j + 1] = __floats2half2_rn(v.z * sc, v.w * sc);
    }
}

__device__ inline float4 ld4(const float* p) { return *(const float4*)p; }
__device__ inline void add4(float4& a, float4 g) {
    a.x += g.x; a.y += g.y; a.z += g.z; a.w += g.w;
}
__device__ inline void bfly4(float4& a, int m) {
    a.x += __shfl_xor(a.x, m);
    a.y += __shfl_xor(a.y, m);
    a.z += __shfl_xor(a.z, m);
    a.w += __shfl_xor(a.w, m);
}
// 8-byte fp16 gather (4 features) -> f32
__device__ inline float4 ldh4(const __half* __restrict__ G, int row, int fo) {
    float2 raw = *(const float2*)(G + (size_t)row * 64 + fo);
    __half2 h0 = *reinterpret_cast<const __half2*>(&raw.x);
    __half2 h1 = *reinterpret_cast<const __half2*>(&raw.y);
    float2 f0 = __half22float2(h0);
    float2 f1 = __half22float2(h1);
    return make_float4(f0.x, f0.y, f1.x, f1.y);
}

// Wave-per-node aggregation, quad-per-edge fp16 gather (8 B/lane).
// lane = 16*q + fcol; quad q handles edge u+q; 16 lanes x 8B = 128B row.
// FINAL=0: Out = __half h1[node][:] = relu(dinv*acc + bias)
// FINAL=1: Out = float d_out[node] = relu(...) . Wl + bl
template <int FINAL>
__global__ __launch_bounds__(256) void agg_k(
    const __half* __restrict__ G, const int* __restrict__ csr,
    const int* __restrict__ offS, const int* __restrict__ offE,
    const float* __restrict__ dinv, const float* __restrict__ bias,
    const float* __restrict__ Wl, const float* __restrict__ bl,
    void* __restrict__ OutP, int n) {
    int lane = threadIdx.x & 63;
    int wid = threadIdx.x >> 6;
    int node = blockIdx.x * 4 + wid;
    if (node >= n) return;

    int q = lane >> 4;
    int fl = (lane & 15) << 2;  // feature base for this lane's 4 features

    float4 a = make_float4(0.f, 0.f, 0.f, 0.f);
    if (q == 0) a = ldh4(G, node, fl);  // self-loop term

    int s0 = offS[node], s1 = offE[node];
    for (int base = s0; base < s1; base += 64) {
        int m = s1 - base;
        if (m > 64) m = 64;
        int e = (lane < m) ? csr[base + lane] : 0;
        int u = 0;
        for (; u + 16 <= m; u += 16) {
            int e0 = __shfl(e, u + q);
            int e1 = __shfl(e, u + 4 + q);
            int e2 = __shfl(e, u + 8 + q);
            int e3 = __shfl(e, u + 12 + q);
            float4 g0 = ldh4(G, e0, fl);
            float4 g1 = ldh4(G, e1, fl);
            float4 g2 = ldh4(G, e2, fl);
            float4 g3 = ldh4(G, e3, fl);
            add4(a, g0); add4(a, g1); add4(a, g2); add4(a, g3);
        }
        for (; u + 4 <= m; u += 4) {
            int e0 = __shfl(e, u + q);
            add4(a, ldh4(G, e0, fl));
        }
        if (u < m) {  // tail of 1..3 edges (u, m wave-uniform)
            int e0 = __shfl(e, (u + q < m) ? (u + q) : 0);
            if (u + q < m) add4(a, ldh4(G, e0, fl));
        }
    }
    // merge quads: butterfly across lane bits 4,5
    bfly4(a, 16);
    bfly4(a, 32);

    float di = dinv[node];
    float4 bv = ld4(bias + fl);
    float4 v;
    v.x = fmaxf(fmaf(di, a.x, bv.x), 0.f);
    v.y = fmaxf(fmaf(di, a.y, bv.y), 0.f);
    v.z = fmaxf(fmaf(di, a.z, bv.z), 0.f);
    v.w = fmaxf(fmaf(di, a.w, bv.w), 0.f);

    if (FINAL) {
        float4 wv = ld4(Wl + fl);
        float p = v.x * wv.x + v.y * wv.y + v.z * wv.z + v.w * wv.w;
#pragma unroll
        for (int d = 8; d > 0; d >>= 1) p += __shfl_xor(p, d);
        if (lane == 0) ((float*)OutP)[node] = p + bl[0];
    } else {
        if (q == 0) {
            __half2 p0 = __floats2half2_rn(v.x, v.y);
            __half2 p1 = __floats2half2_rn(v.z, v.w);
            float2 packed;
            packed.x = *reinterpret_cast<float*>(&p0);
            packed.y = *reinterpret_cast<float*>(&p1);
            *(float2*)((__half*)OutP + (size_t)node * 64 + fl) = packed;
        }
    }
}

extern "C" void kernel_launch(void* const* d_in, const int* in_sizes, int n_in,
                              void* d_out, int out_size, void* d_ws, size_t ws_size,
                              hipStream_t stream) {
    const float* x  = (const float*)d_in[0];
    const int*   ei = (const int*)d_in[1];
    const float* W1 = (const float*)d_in[2];
    const float* b1 = (const float*)d_in[3];
    const float* W2 = (const float*)d_in[4];
    const float* b2 = (const float*)d_in[5];
    const float* Wl = (const float*)d_in[6];
    const float* bl = (const float*)d_in[7];

    const int N = in_sizes[0] / 64;
    const int E = in_sizes[1] / 2;
    const int* src = ei;
    const int* dst = ei + E;
    const int NB = (N + 127) >> 7;         // 782 buckets (<=1024 assumed)
    const int FB = (E + EBLK - 1) / EBLK;  // 391

    char* w = (char*)d_ws;
    size_t o = 0;
    auto take = [&](size_t bytes) {
        void* p = w + o;
        o = (o + bytes + 255) & ~(size_t)255;
        return p;
    };
    int*    bcur = (int*)take((size_t)NB * 4);
    float*  dinv = (float*)take((size_t)N * 4);
    int*    offS = (int*)take((size_t)N * 4);
    int*    offE = (int*)take((size_t)N * 4);
    int*    csr  = (int*)take((size_t)NB * CAP * 4);   // 19.2 MB (holey)
    int*    ebuf = (int*)take((size_t)NB * CAP * 4);   // 19.2 MB
    __half* G    = (__half*)take((size_t)N * 64 * 2);  // 12.8 MB
    __half* h1   = (__half*)take((size_t)N * 64 * 2);  // 12.8 MB

    hipMemsetAsync(bcur, 0, (size_t)NB * 4, stream);
    bfill_k<<<FB, 256, 0, stream>>>(src, dst, bcur, ebuf, E);
    csr2_k<<<2 * NB, 256, 0, stream>>>(ebuf, bcur, offS, offE, csr, dinv, N);

    // Layer 1
    gemm64h_k<float><<<(N + 255) / 256, 256, 0, stream>>>(x, W1, dinv, G, N);
    agg_k<0><<<(N + 3) / 4, 256, 0, stream>>>(G, csr, offS, offE, dinv, b1,
                                              nullptr, nullptr, h1, N);
    // Layer 2 + fused linear head
    gemm64h_k<__half><<<(N + 255) / 256, 256, 0, stream>>>(h1, W2, dinv, G, N);
    agg_k<1><<<(N + 3) / 4, 256, 0, stream>>>(G, csr, offS, offE, dinv, b2,
                                              Wl, bl, d_out, N);
}